// Round 1
// baseline (334.092 us; speedup 1.0000x reference)
//
#include <hip/hip_runtime.h>

#define NN 4096     // nodes
#define HC 8        // heads
#define DC 32       // dim per head
#define OC 256      // out channels = HC*DC
#define KC 256      // in channels
#define CF 6        // curvature features

typedef __bf16 bf16_t;
typedef bf16_t bf16x8 __attribute__((ext_vector_type(8)));
typedef float f32x4 __attribute__((ext_vector_type(4)));
typedef float f32x2 __attribute__((ext_vector_type(2)));
typedef unsigned u32x4 __attribute__((ext_vector_type(4)));

#if defined(__has_builtin)
#if __has_builtin(__builtin_amdgcn_exp2f)
#define EXP2F(x) __builtin_amdgcn_exp2f(x)
#else
#define EXP2F(x) exp2f(x)
#endif
#else
#define EXP2F(x) exp2f(x)
#endif

// bf16 pair (one dword: lo16 = t_even, hi16 = t_odd) -> f32x2 (bf16 is
// truncated f32: unpack = 1 shl + 1 and).
static __device__ __forceinline__ f32x2 unpk(unsigned dw) {
  union { unsigned u; float f; } lo, hi;
  lo.u = dw << 16;
  hi.u = dw & 0xffff0000u;
  return (f32x2){lo.f, hi.f};
}

// ---------------------------------------------------------------------------
// Kernel 1: heterogeneous prep (unchanged since R8).
// Blocks 0..511 (gemm role): h-GEMM (64 rows x 1 head) + e_l (f32) +
//   e_r packed bf16 in attn's lane order (erP[c][q][h][t8]) + V as bf16 in
//   attn's B-fragment order (hT2[head][c][q][d32][t8]).
// Blocks 512..2559 (pack role): ballot-pack adj -> 2MB bitmask; cfT (f32,
//   i-side) + cfP packed bf16 in attn's lane order (cfP[c][q][f][t8]); Wc2.
// ---------------------------------------------------------------------------
__global__ __launch_bounds__(256) void prep_all(const float* __restrict__ x,
                                                const float* __restrict__ W,
                                                const float* __restrict__ a_l,
                                                const float* __restrict__ a_r,
                                                const int* __restrict__ adj,
                                                const float* __restrict__ cfeat,
                                                const float* __restrict__ Wc,
                                                const float* __restrict__ gate,
                                                float* __restrict__ e_l2,
                                                bf16_t* __restrict__ erP,
                                                bf16_t* __restrict__ hT2,
                                                unsigned* __restrict__ adjb,
                                                float* __restrict__ cfT,
                                                bf16_t* __restrict__ cfP,
                                                float* __restrict__ Wc2) {
  __shared__ float As[16][68];   // [k][i]
  __shared__ float Bs[16][36];   // [k][c]
  __shared__ float Ct[DC][65];   // [c][i]
  const float LOG2E = 1.44269504088896340736f;
  const int t = threadIdx.x;
  const int bid = blockIdx.x;

  if (bid >= 512) {
    // ---------------- pack role ----------------
    const int pb = bid - 512;                    // 0..2047
    const int ptid = pb * 256 + t;
    const int lane = t & 63;
    const int wv = pb * 4 + (t >> 6);            // 0..8191
    for (int it = 0; it < 32; ++it) {
      int g = wv * 32 + it;                      // segment id
      int i = g >> 6;
      int s = g & 63;
      int v = adj[(size_t)i * NN + s * 64 + lane];
      unsigned long long m = __ballot(v > 0);
      if (lane == 0) *(unsigned long long*)(adjb + i * 128 + s * 2) = m;
    }
    if (ptid < NN * CF) {
      int j = ptid / CF, f = ptid - j * CF;
      float v = cfeat[ptid];
      cfT[f * NN + j] = v;
      int cc = j >> 5, qq = (j >> 3) & 3, tt = j & 7;
      cfP[((cc * 4 + qq) * CF + f) * 8 + tt] = (bf16_t)v;
    }
    if (ptid < HC * CF) Wc2[ptid] = Wc[ptid] * gate[0] * LOG2E;
    return;
  }

  // ---------------- gemm role ----------------
  const int i0 = (bid & 63) * 64;
  const int head = bid >> 6;
  const int c0 = head * DC;
  const int tx = t & 7;          // col group (4 cols)
  const int ty = t >> 3;         // row pair (2 rows)
  const int lr = t >> 2;         // staging row 0..63
  const int lk = (t & 3) * 4;    // staging k 0,4,8,12

  float acc[2][4] = {};
  for (int kk = 0; kk < KC; kk += 16) {
    f32x4 av = *(const f32x4*)&x[(size_t)(i0 + lr) * KC + kk + lk];
    f32x4 wv;
    if (t < 128) wv = *(const f32x4*)&W[(size_t)(c0 + (t >> 2)) * KC + kk + lk];
    __syncthreads();
    As[lk + 0][lr] = av[0]; As[lk + 1][lr] = av[1];
    As[lk + 2][lr] = av[2]; As[lk + 3][lr] = av[3];
    if (t < 128) {
      int br = t >> 2;
      Bs[lk + 0][br] = wv[0]; Bs[lk + 1][br] = wv[1];
      Bs[lk + 2][br] = wv[2]; Bs[lk + 3][br] = wv[3];
    }
    __syncthreads();
#pragma unroll
    for (int k = 0; k < 16; ++k) {
      f32x2 a = *(const f32x2*)&As[k][ty * 2];
      f32x4 b = *(const f32x4*)&Bs[k][tx * 4];
#pragma unroll
      for (int r = 0; r < 2; ++r)
#pragma unroll
        for (int u = 0; u < 4; ++u)
          acc[r][u] += a[r] * b[u];
    }
  }

  // e_l (f32) / e_r (packed bf16, attn lane order), reduce across 8 tx lanes
  f32x4 al4 = *(const f32x4*)&a_l[c0 + tx * 4];
  f32x4 ar4 = *(const f32x4*)&a_r[c0 + tx * 4];
#pragma unroll
  for (int r = 0; r < 2; ++r) {
    float el = acc[r][0] * al4[0] + acc[r][1] * al4[1] +
               acc[r][2] * al4[2] + acc[r][3] * al4[3];
    float er = acc[r][0] * ar4[0] + acc[r][1] * ar4[1] +
               acc[r][2] * ar4[2] + acc[r][3] * ar4[3];
    el += __shfl_xor(el, 1, 64); el += __shfl_xor(el, 2, 64); el += __shfl_xor(el, 4, 64);
    er += __shfl_xor(er, 1, 64); er += __shfl_xor(er, 2, 64); er += __shfl_xor(er, 4, 64);
    if (tx == 0) {
      int j = i0 + ty * 2 + r;
      e_l2[j * HC + head] = el * LOG2E;
      int cc = j >> 5, qq = (j >> 3) & 3, tt = j & 7;
      erP[((cc * 4 + qq) * HC + head) * 8 + tt] = (bf16_t)(er * LOG2E);
    }
  }

  // transpose to B-fragment layout via LDS
#pragma unroll
  for (int r = 0; r < 2; ++r)
#pragma unroll
    for (int u = 0; u < 4; ++u)
      Ct[tx * 4 + u][ty * 2 + r] = acc[r][u];
  __syncthreads();
  const size_t base = (size_t)head * (NN / 32) * 1024 + (size_t)(bid & 63) * 2048;
#pragma unroll
  for (int rep = 0; rep < 8; ++rep) {
    int idx = rep * 256 + t;                 // enumerates [chunkL][q][d][t8]
    int dd = (idx >> 3) & 31;
    int jl = (idx >> 10) * 32 + ((idx >> 8) & 3) * 8 + (idx & 7);
    hT2[base + idx] = (bf16_t)Ct[dd][jl];
  }
}

// ---------------------------------------------------------------------------
// Kernel 2: fused masked attention. R14: 4 heads/block (was 2), 512 threads
// (8 waves, each owning j-chunks c ≡ w mod 8 -> 16 iterations), grid (256,2).
// Rationale: kernel is VALU-issue-bound (VALUBusy 64%, MfmaUtil 3.3%, HBM
// 1.6%); the head-independent |cf_i - cf_j| unpack/sub/abs (~40% of inner
// slots) was replicated across gridDim.y=4 head-pair blocks. Sharing it over
// 4 heads cuts per-wave issue slots ~0.64x. Total waves unchanged (4096);
// lb(512,4) targets <=128 VGPR -> 2 blocks/CU -> 16 waves/CU as before.
// Inner loop reordered p-outer so |d| temps die per-p (register control);
// p=3 er-unpacks hoisted so next-iter cf/er/adj register prefetch still
// issues ~200cyc ahead of first use (everything is L2-resident).
// No online max (logits bounded, masked p == 0 exactly).
// ---------------------------------------------------------------------------
__global__ __launch_bounds__(512, 4) void attn(const unsigned* __restrict__ adjb,
                                               const float* __restrict__ e_l2,
                                               const float* __restrict__ cfT,
                                               const float* __restrict__ Wc2,
                                               const u32x4* __restrict__ cfP4,
                                               const u32x4* __restrict__ erP4,
                                               const bf16_t* __restrict__ hT2,
                                               float* __restrict__ out) {
  __shared__ float Obuf[16][128];
  __shared__ float Sbuf[16][4];
  const int tid = threadIdx.x;
  const int w = tid >> 6;        // 0..7
  const int lane = tid & 63;
  const int il = lane & 15;
  const int quad = lane >> 4;
  const int ibase = blockIdx.x * 16;
  const int hg = blockIdx.y;     // head quad: heads hg*4 .. hg*4+3
  const int i = ibase + il;
  const int HSTRIDE = (NN / 32) * 1024;   // per-head stride in hT2

  for (int idx = tid; idx < 16 * 128; idx += 512) (&Obuf[0][0])[idx] = 0.f;
  if (tid < 64) (&Sbuf[0][0])[tid] = 0.f;
  __syncthreads();

  f32x2 cfi2[CF];
#pragma unroll
  for (int f = 0; f < CF; ++f) { float v = cfT[f * NN + i]; cfi2[f] = (f32x2){v, v}; }
  f32x2 el2[4];
  {
    f32x4 e0 = *(const f32x4*)&e_l2[i * HC + hg * 4];
#pragma unroll
    for (int u = 0; u < 4; ++u) el2[u] = (f32x2){e0[u], e0[u]};
  }
  float wc[4][CF];
#pragma unroll
  for (int h = 0; h < 4; ++h)
#pragma unroll
    for (int f = 0; f < CF; ++f) wc[h][f] = Wc2[(hg * 4 + h) * CF + f];

  f32x4 acc[4][2];
#pragma unroll
  for (int h = 0; h < 4; ++h)
#pragma unroll
    for (int d = 0; d < 2; ++d) acc[h][d] = (f32x4){0.f, 0.f, 0.f, 0.f};
  f32x2 S2[4];
#pragma unroll
  for (int h = 0; h < 4; ++h) S2[h] = (f32x2){0.f, 0.f};

  const bf16_t* hTbase = hT2 + (size_t)hg * 4 * HSTRIDE + quad * 256 + il * 8;
  const u32x4* cfb = cfP4 + quad * CF;           // c-stride 4*CF  (u32x4 units)
  const u32x4* erb = erP4 + quad * HC + hg * 4;  // c-stride 4*HC
  const unsigned* adjrow = adjb + i * 128;

  // ---- prime the prefetch registers for chunk c = w ----
  u32x4 cfc[CF];
#pragma unroll
  for (int f = 0; f < CF; ++f) cfc[f] = cfb[w * (4 * CF) + f];
  u32x4 erc[4];
#pragma unroll
  for (int h = 0; h < 4; ++h) erc[h] = erb[w * (4 * HC) + h];
  unsigned mc = adjrow[w];

#pragma unroll 2
  for (int c = w; c < NN / 32; c += 8) {
    // V fragments: issued at body top, consumed by MFMA at the end
    const bf16_t* bp = hTbase + c * 1024;
    bf16x8 bfr[4][2];
#pragma unroll
    for (int h = 0; h < 4; ++h) {
      bfr[h][0] = *(const bf16x8*)(bp + h * HSTRIDE);
      bfr[h][1] = *(const bf16x8*)(bp + h * HSTRIDE + 128);
    }

    const unsigned m8 = (mc >> (quad * 8)) & 0xffu;   // mc dead after this
    bf16x8 af[4];                                     // P fragments (built over p)

#pragma unroll
    for (int p = 0; p < 4; ++p) {
      // shared across 4 heads: |cf_i - cf_j| for the j-pair
      f32x2 ab[CF];
#pragma unroll
      for (int f = 0; f < CF; ++f) {
        f32x2 d2 = cfi2[f] - unpk(cfc[f][p]);
        ab[f] = __builtin_elementwise_max(d2, -d2);
      }
      f32x2 mf2 = (f32x2){(float)((m8 >> (2 * p)) & 1u),
                          (float)((m8 >> (2 * p + 1)) & 1u)};
      // leaky pre-sum (consumes erc[h][p]); hoisted so the p==3 prefetch
      // below issues after the final erc read
      f32x2 sv[4];
#pragma unroll
      for (int h = 0; h < 4; ++h) sv[h] = el2[h] + unpk(erc[h][p]);

      if (p == 3) {
        // ---- prefetch chunk c+8 (all cfc/erc/mc reads complete) ----
        const int cn = (c + 8) & (NN / 32 - 1);
#pragma unroll
        for (int f = 0; f < CF; ++f) cfc[f] = cfb[cn * (4 * CF) + f];
#pragma unroll
        for (int h = 0; h < 4; ++h) erc[h] = erb[cn * (4 * HC) + h];
        mc = adjrow[cn];
      }

#pragma unroll
      for (int h = 0; h < 4; ++h) {
        f32x2 a = __builtin_elementwise_max(sv[h], 0.2f * sv[h]);
#pragma unroll
        for (int f = 0; f < CF; ++f) {
          f32x2 wsp = (f32x2){wc[h][f], wc[h][f]};
          a = __builtin_elementwise_fma(ab[f], wsp, a);
        }
        f32x2 pv = (f32x2){EXP2F(a[0]), EXP2F(a[1])};
        pv = pv * mf2;           // masked p == 0 exactly
        S2[h] += pv;
        af[h][2 * p] = (bf16_t)pv[0];
        af[h][2 * p + 1] = (bf16_t)pv[1];
      }
    }

#pragma unroll
    for (int h = 0; h < 4; ++h) {
      acc[h][0] = __builtin_amdgcn_mfma_f32_16x16x32_bf16(af[h], bfr[h][0], acc[h][0], 0, 0, 0);
      acc[h][1] = __builtin_amdgcn_mfma_f32_16x16x32_bf16(af[h], bfr[h][1], acc[h][1], 0, 0, 0);
    }
  }

  // reduce S across quads (lanes il, il+16, il+32, il+48), then across waves
#pragma unroll
  for (int h = 0; h < 4; ++h) {
    float v = S2[h][0] + S2[h][1];
    v += __shfl_xor(v, 16, 64);
    v += __shfl_xor(v, 32, 64);
    if (quad == 0) atomicAdd(&Sbuf[il][h], v);
  }
  // accumulate O partials: C/D layout row = quad*4+r (i), col = il (d half)
#pragma unroll
  for (int h = 0; h < 4; ++h)
#pragma unroll
    for (int dh = 0; dh < 2; ++dh)
#pragma unroll
      for (int r = 0; r < 4; ++r)
        atomicAdd(&Obuf[quad * 4 + r][h * DC + dh * 16 + il], acc[h][dh][r]);
  __syncthreads();

  // epilogue: divide by softmax denom, coalesced store
  for (int idx = tid; idx < 16 * 128; idx += 512) {
    int row = idx >> 7;
    int colg = idx & 127;
    out[(size_t)(ibase + row) * OC + hg * 128 + colg] =
        Obuf[row][colg] / Sbuf[row][colg >> 5];
  }
}

// ---------------------------------------------------------------------------
extern "C" void kernel_launch(void* const* d_in, const int* in_sizes, int n_in,
                              void* d_out, int out_size, void* d_ws, size_t ws_size,
                              hipStream_t stream) {
  const float* x    = (const float*)d_in[0];
  // d_in[1] = positions — unused by the reference
  const float* cfeat= (const float*)d_in[2];
  const int*   adj  = (const int*)d_in[3];
  const float* W    = (const float*)d_in[4];
  const float* a_l  = (const float*)d_in[5];
  const float* a_r  = (const float*)d_in[6];
  const float* Wc   = (const float*)d_in[7];
  const float* gate = (const float*)d_in[8];
  float* out = (float*)d_out;

  char* ws = (char*)d_ws;
  bf16_t*   hT2  = (bf16_t*)ws;                              // 2 MB
  unsigned* adjb = (unsigned*)(ws + (2u << 20));             // 2 MB
  float*    e_l2 = (float*)(ws + (4u << 20));                // 128 KB
  float*    cfT  = (float*)(ws + (4u << 20) + (128u << 10)); // 96 KB
  float*    Wc2  = (float*)(ws + (4u << 20) + (256u << 10)); // 192 B
  bf16_t*   cfP  = (bf16_t*)(ws + (4u << 20) + (320u << 10));// 48 KB
  bf16_t*   erP  = (bf16_t*)(ws + (4u << 20) + (384u << 10));// 64 KB

  prep_all<<<2560, 256, 0, stream>>>(x, W, a_l, a_r, adj, cfeat, Wc, gate,
                                     e_l2, erP, hT2, adjb, cfT, cfP, Wc2);
  attn<<<dim3(NN / 16, 2), 512, 0, stream>>>(adjb, e_l2, cfT, Wc2,
                                             (const u32x4*)cfP, (const u32x4*)erP,
                                             hT2, out);
}

// Round 2
// 245.581 us; speedup vs baseline: 1.3604x; 1.3604x over previous
//
#include <hip/hip_runtime.h>

#define NN 4096     // nodes
#define HC 8        // heads
#define DC 32       // dim per head
#define OC 256      // out channels = HC*DC
#define KC 256      // in channels
#define CF 6        // curvature features

typedef __bf16 bf16_t;
typedef bf16_t bf16x8 __attribute__((ext_vector_type(8)));
typedef float f32x4 __attribute__((ext_vector_type(4)));
typedef float f32x2 __attribute__((ext_vector_type(2)));
typedef unsigned u32x4 __attribute__((ext_vector_type(4)));
typedef unsigned u32x2 __attribute__((ext_vector_type(2)));

#if defined(__has_builtin)
#if __has_builtin(__builtin_amdgcn_exp2f)
#define EXP2F(x) __builtin_amdgcn_exp2f(x)
#else
#define EXP2F(x) exp2f(x)
#endif
#else
#define EXP2F(x) exp2f(x)
#endif

// bf16 pair (one dword: lo16 = even elem, hi16 = odd elem) -> f32x2.
static __device__ __forceinline__ f32x2 unpk(unsigned dw) {
  union { unsigned u; float f; } lo, hi;
  lo.u = dw << 16;
  hi.u = dw & 0xffff0000u;
  return (f32x2){lo.f, hi.f};
}

// ---------------------------------------------------------------------------
// Kernel 1: heterogeneous prep.
// Blocks 0..511 (gemm role): h-GEMM (64 rows x 1 head) + e_l (f32, [i][h]) +
//   e_r (f32, transposed [h][j] for the attn MFMA C-operand) + V as bf16 in
//   attn's B-fragment order (hT2[head][c][q][d32][t8]).
// Blocks 512..2559 (pack role): ballot-pack adj -> 2MB bitmask; cfR (bf16
//   rows [j][8], f<6 valid, padded 0) for the bias-MFMA B-operand; wcA =
//   block-diagonal wc*gate*LOG2E constant in A-fragment layout
//   (A[row=hl*4+jj][k=jj'*8+f] = (jj==jj' && f<6) ? wc[hg*4+hl][f] : 0).
// ---------------------------------------------------------------------------
__global__ __launch_bounds__(256) void prep_all(const float* __restrict__ x,
                                                const float* __restrict__ W,
                                                const float* __restrict__ a_l,
                                                const float* __restrict__ a_r,
                                                const int* __restrict__ adj,
                                                const float* __restrict__ cfeat,
                                                const float* __restrict__ Wc,
                                                const float* __restrict__ gate,
                                                float* __restrict__ e_l2,
                                                float* __restrict__ erT,
                                                bf16_t* __restrict__ hT2,
                                                unsigned* __restrict__ adjb,
                                                bf16_t* __restrict__ cfR,
                                                bf16_t* __restrict__ wcA) {
  __shared__ float As[16][68];   // [k][i]
  __shared__ float Bs[16][36];   // [k][c]
  __shared__ float Ct[DC][65];   // [c][i]
  const float LOG2E = 1.44269504088896340736f;
  const int t = threadIdx.x;
  const int bid = blockIdx.x;

  if (bid >= 512) {
    // ---------------- pack role ----------------
    const int pb = bid - 512;                    // 0..2047
    const int ptid = pb * 256 + t;
    const int lane = t & 63;
    const int wv = pb * 4 + (t >> 6);            // 0..8191
    for (int it = 0; it < 32; ++it) {
      int g = wv * 32 + it;                      // segment id
      int i = g >> 6;
      int s = g & 63;
      int v = adj[(size_t)i * NN + s * 64 + lane];
      unsigned long long m = __ballot(v > 0);
      if (lane == 0) *(unsigned long long*)(adjb + i * 128 + s * 2) = m;
    }
    if (ptid < NN) {
      int j = ptid;
#pragma unroll
      for (int f = 0; f < CF; ++f) cfR[j * 8 + f] = (bf16_t)cfeat[j * CF + f];
      cfR[j * 8 + 6] = (bf16_t)0.f;
      cfR[j * 8 + 7] = (bf16_t)0.f;
    }
    if (ptid < 128) {
      int ln = ptid & 63, hg = ptid >> 6;
      int row = ln & 15, jjp = ln >> 4;
      int hl = row >> 2, jj = row & 3;
      float gs = gate[0] * LOG2E;
#pragma unroll
      for (int e = 0; e < 8; ++e) {
        float v = (jj == jjp && e < CF) ? Wc[(hg * 4 + hl) * CF + e] * gs : 0.f;
        wcA[(hg * 64 + ln) * 8 + e] = (bf16_t)v;
      }
    }
    return;
  }

  // ---------------- gemm role ----------------
  const int i0 = (bid & 63) * 64;
  const int head = bid >> 6;
  const int c0 = head * DC;
  const int tx = t & 7;          // col group (4 cols)
  const int ty = t >> 3;         // row pair (2 rows)
  const int lr = t >> 2;         // staging row 0..63
  const int lk = (t & 3) * 4;    // staging k 0,4,8,12

  float acc[2][4] = {};
  for (int kk = 0; kk < KC; kk += 16) {
    f32x4 av = *(const f32x4*)&x[(size_t)(i0 + lr) * KC + kk + lk];
    f32x4 wv;
    if (t < 128) wv = *(const f32x4*)&W[(size_t)(c0 + (t >> 2)) * KC + kk + lk];
    __syncthreads();
    As[lk + 0][lr] = av[0]; As[lk + 1][lr] = av[1];
    As[lk + 2][lr] = av[2]; As[lk + 3][lr] = av[3];
    if (t < 128) {
      int br = t >> 2;
      Bs[lk + 0][br] = wv[0]; Bs[lk + 1][br] = wv[1];
      Bs[lk + 2][br] = wv[2]; Bs[lk + 3][br] = wv[3];
    }
    __syncthreads();
#pragma unroll
    for (int k = 0; k < 16; ++k) {
      f32x2 a = *(const f32x2*)&As[k][ty * 2];
      f32x4 b = *(const f32x4*)&Bs[k][tx * 4];
#pragma unroll
      for (int r = 0; r < 2; ++r)
#pragma unroll
        for (int u = 0; u < 4; ++u)
          acc[r][u] += a[r] * b[u];
    }
  }

  // e_l (f32 [i][h]) / e_r (f32, transposed [h][j]); reduce across 8 tx lanes
  f32x4 al4 = *(const f32x4*)&a_l[c0 + tx * 4];
  f32x4 ar4 = *(const f32x4*)&a_r[c0 + tx * 4];
#pragma unroll
  for (int r = 0; r < 2; ++r) {
    float el = acc[r][0] * al4[0] + acc[r][1] * al4[1] +
               acc[r][2] * al4[2] + acc[r][3] * al4[3];
    float er = acc[r][0] * ar4[0] + acc[r][1] * ar4[1] +
               acc[r][2] * ar4[2] + acc[r][3] * ar4[3];
    el += __shfl_xor(el, 1, 64); el += __shfl_xor(el, 2, 64); el += __shfl_xor(el, 4, 64);
    er += __shfl_xor(er, 1, 64); er += __shfl_xor(er, 2, 64); er += __shfl_xor(er, 4, 64);
    if (tx == 0) {
      int j = i0 + ty * 2 + r;
      e_l2[j * HC + head] = el * LOG2E;
      erT[head * NN + j] = er * LOG2E;
    }
  }

  // transpose to B-fragment layout via LDS
#pragma unroll
  for (int r = 0; r < 2; ++r)
#pragma unroll
    for (int u = 0; u < 4; ++u)
      Ct[tx * 4 + u][ty * 2 + r] = acc[r][u];
  __syncthreads();
  const size_t base = (size_t)head * (NN / 32) * 1024 + (size_t)(bid & 63) * 2048;
#pragma unroll
  for (int rep = 0; rep < 8; ++rep) {
    int idx = rep * 256 + t;                 // enumerates [chunkL][q][d][t8]
    int dd = (idx >> 3) & 31;
    int jl = (idx >> 10) * 32 + ((idx >> 8) & 3) * 8 + (idx & 7);
    hT2[base + idx] = (bf16_t)Ct[dd][jl];
  }
}

// ---------------------------------------------------------------------------
// Kernel 2: fused masked attention, R15: bias via MFMA.
// R14 post-mortem: 4-head VALU sharing at lb(512,4) spilled (~170 live VGPR
// vs 128 cap): WRITE_SIZE 4->331MB = scratch traffic. R15 removes the VALU
// work instead of replicating it: the wc-dot (the largest per-head VALU term)
// and the leaky/e_l/e_r add run through mfma_16x16x32_bf16 with a
// block-diagonal wc constant:
//   A[row=hl*4+jj][k=jj'*8+f] = (jj==jj')?wc2[h][f]:0   (const, 1 frag/lane)
//   B[k=q*8+f][col=i]         = |cf_i[f]-cf_{j0+q}[f]|  (3 pk_sub+3 cvt_pk)
//   C[row][col=i]             = leaky(el[i,h]+er[j,h])  (f32 - better than R13)
// One MFMA = 16 i x 4 j x 4 heads of logits. Lane (q,il) owns head hg*4+q,
// 4 j's: exp2/mask/S stay lane-local. P is repacked head->j-slice via a
// per-wave private 4KB LDS buffer (barrier-free: same-wave DS ordering),
// p-index XOR-swizzled by ((il+hl)&3)<<2 to spread banks; PV consumes hT2
// exactly as the proven R13 path. Est ~105 VGPR at lb(512,4), 40KB LDS,
// 2 blocks/CU = 16 waves/CU (R13-proven occupancy).
// Failure signals: WRITE_SIZE >> 4MB = spill; big SQ_LDS_BANK_CONFLICT =
// swizzle insufficient.
// ---------------------------------------------------------------------------
__global__ __launch_bounds__(512, 4) void attn(const unsigned* __restrict__ adjb,
                                               const float* __restrict__ e_l2,
                                               const float* __restrict__ erT,
                                               const float* __restrict__ cfeat,
                                               const bf16_t* __restrict__ cfR,
                                               const bf16_t* __restrict__ wcA,
                                               const bf16_t* __restrict__ hT2,
                                               float* __restrict__ out) {
  __shared__ unsigned Pl[8][1024];   // per-wave P exchange: [hl(4)][i(16)][p(16)]
  __shared__ float Obuf[16][128];
  __shared__ float Sbuf[16][4];
  const int tid = threadIdx.x;
  const int w = tid >> 6;        // 0..7: wave owns chunks c == w (mod 8)
  const int lane = tid & 63;
  const int il = lane & 15;      // bias: i (local); PV: d-index
  const int q = lane >> 4;       // bias: head-local; PV: j-slice quad
  const int ibase = blockIdx.x * 16;
  const int hg = blockIdx.y;     // head quad: heads hg*4 .. hg*4+3
  const int i = ibase + il;
  const int h = hg * 4 + q;      // this lane's bias-head
  const int HSTRIDE = (NN / 32) * 1024;

  for (int idx = tid; idx < 16 * 128; idx += 512) (&Obuf[0][0])[idx] = 0.f;
  if (tid < 64) (&Sbuf[0][0])[tid] = 0.f;
  __syncthreads();

  // lane constants
  f32x2 cfi2[3];
#pragma unroll
  for (int tt = 0; tt < 3; ++tt)
    cfi2[tt] = *(const f32x2*)&cfeat[i * CF + 2 * tt];
  const float elv = e_l2[i * HC + h];
  const f32x4 ev4 = (f32x4){elv, elv, elv, elv};
  const bf16x8 wA = *(const bf16x8*)&wcA[(hg * 64 + lane) * 8];
  const unsigned* adjrow = adjb + i * 128;
  unsigned* Pw = &Pl[w][0];

  f32x4 acc[4][2];
#pragma unroll
  for (int hl = 0; hl < 4; ++hl)
#pragma unroll
    for (int d = 0; d < 2; ++d) acc[hl][d] = (f32x4){0.f, 0.f, 0.f, 0.f};
  f32x2 S2 = (f32x2){0.f, 0.f};

  unsigned mc = adjrow[w];     // mask prefetch
  for (int c = w; c < NN / 32; c += 8) {
    const unsigned madj = mc;
    mc = adjrow[(c + 8) & (NN / 32 - 1)];

    // -------- stage 1: 8 bias-MFMAs (4 j's x 4 heads x 16 i each) --------
#pragma unroll
    for (int m = 0; m < 8; ++m) {
      const int j0 = c * 32 + m * 4;
      union { bf16x8 v; u32x4 u; } cj;
      cj.v = *(const bf16x8*)&cfR[(size_t)(j0 + q) * 8];
      const f32x4 er4 = *(const f32x4*)&erT[(size_t)h * NN + j0];

      union { bf16x8 v; u32x4 u; } uf;     // B-operand: |cf_i - cf_j|
#pragma unroll
      for (int tt = 0; tt < 3; ++tt) {
        f32x2 d2 = cfi2[tt] - unpk(cj.u[tt]);
        f32x2 ab = __builtin_elementwise_max(d2, -d2);
        uf.v[2 * tt] = (bf16_t)ab[0];
        uf.v[2 * tt + 1] = (bf16_t)ab[1];
      }
      uf.u[3] = 0u;                        // k=f 6,7: wcA rows are zero (dc)

      f32x4 sv = er4 + ev4;                // C: leaky(el+er), f32 exact
      f32x4 cin = __builtin_elementwise_max(sv, 0.2f * sv);
      f32x4 dD = __builtin_amdgcn_mfma_f32_16x16x32_bf16(wA, uf.v, cin, 0, 0, 0);

      const unsigned mb = (madj >> (m * 4)) & 0xfu;
      f32x4 pv;
#pragma unroll
      for (int r = 0; r < 4; ++r)
        pv[r] = ((mb >> r) & 1u) ? EXP2F(dD[r]) : 0.f;
      S2 += (f32x2){pv[0], pv[1]} + (f32x2){pv[2], pv[3]};

      union { bf16_t b[2]; unsigned u; } w0, w1;
      w0.b[0] = (bf16_t)pv[0]; w0.b[1] = (bf16_t)pv[1];
      w1.b[0] = (bf16_t)pv[2]; w1.b[1] = (bf16_t)pv[3];
      // store j-pairs 2m,2m+1 for head-local q; p XOR-swizzled for banks
      const int off = (q * 16 + il) * 16 + ((2 * m) ^ (((il + q) & 3) << 2));
      *(u32x2*)(Pw + off) = (u32x2){w0.u, w1.u};
    }

    // -------- stage 2: PV (same-wave DS ordering; no barrier) --------
#pragma unroll
    for (int hl = 0; hl < 4; ++hl) {
      const int roff = (hl * 16 + il) * 16 + ((q * 4) ^ (((il + hl) & 3) << 2));
      bf16x8 af = *(const bf16x8*)(Pw + roff);
      const bf16_t* bp = hT2 + (size_t)(hg * 4 + hl) * HSTRIDE + c * 1024 + q * 256 + il * 8;
      bf16x8 b0 = *(const bf16x8*)bp;
      bf16x8 b1 = *(const bf16x8*)(bp + 128);
      acc[hl][0] = __builtin_amdgcn_mfma_f32_16x16x32_bf16(af, b0, acc[hl][0], 0, 0, 0);
      acc[hl][1] = __builtin_amdgcn_mfma_f32_16x16x32_bf16(af, b1, acc[hl][1], 0, 0, 0);
    }
  }

  // S: lane (q,il) owns head q fully for its chunks -> one atomic per lane
  atomicAdd(&Sbuf[il][q], S2[0] + S2[1]);
  // O partials: PV C/D layout row = q*4+r (i), col = il (d half)
#pragma unroll
  for (int hl = 0; hl < 4; ++hl)
#pragma unroll
    for (int dh = 0; dh < 2; ++dh)
#pragma unroll
      for (int r = 0; r < 4; ++r)
        atomicAdd(&Obuf[q * 4 + r][hl * DC + dh * 16 + il], acc[hl][dh][r]);
  __syncthreads();

  // epilogue: divide by softmax denom, coalesced store
  for (int idx = tid; idx < 16 * 128; idx += 512) {
    int row = idx >> 7;
    int colg = idx & 127;
    out[(size_t)(ibase + row) * OC + hg * 128 + colg] =
        Obuf[row][colg] / Sbuf[row][colg >> 5];
  }
}

// ---------------------------------------------------------------------------
extern "C" void kernel_launch(void* const* d_in, const int* in_sizes, int n_in,
                              void* d_out, int out_size, void* d_ws, size_t ws_size,
                              hipStream_t stream) {
  const float* x    = (const float*)d_in[0];
  // d_in[1] = positions — unused by the reference
  const float* cfeat= (const float*)d_in[2];
  const int*   adj  = (const int*)d_in[3];
  const float* W    = (const float*)d_in[4];
  const float* a_l  = (const float*)d_in[5];
  const float* a_r  = (const float*)d_in[6];
  const float* Wc   = (const float*)d_in[7];
  const float* gate = (const float*)d_in[8];
  float* out = (float*)d_out;

  char* ws = (char*)d_ws;
  bf16_t*   hT2  = (bf16_t*)ws;                              // 2 MB
  unsigned* adjb = (unsigned*)(ws + (2u << 20));             // 2 MB
  float*    e_l2 = (float*)(ws + (4u << 20));                // 128 KB
  float*    erT  = (float*)(ws + (4u << 20) + (128u << 10)); // 128 KB
  bf16_t*   cfR  = (bf16_t*)(ws + (4u << 20) + (256u << 10));// 64 KB
  bf16_t*   wcA  = (bf16_t*)(ws + (4u << 20) + (320u << 10));// 2 KB

  prep_all<<<2560, 256, 0, stream>>>(x, W, a_l, a_r, adj, cfeat, Wc, gate,
                                     e_l2, erT, hT2, adjb, cfR, wcA);
  attn<<<dim3(NN / 16, 2), 512, 0, stream>>>(adjb, e_l2, erT, cfeat,
                                             cfR, wcA, hT2, out);
}